// Round 6
// baseline (197.277 us; speedup 1.0000x reference)
//
#include <hip/hip_runtime.h>
#include <hip/hip_bf16.h>

// MMD loss: source/target 4096x256 fp32, output = scalar fp32. N=8192, D=256.
//
// Two kernels total (last-block tickets fuse the scalar stages):
//  k_prep : fp32 -> bf16 in MFMA-native tiled layout G2 + row sq[] (from the
//           SAME bf16 values -> diagonal exact) + colsum/sqsum atomics;
//           LAST block computes neg_gamma2 = -log2(e)/(16*bw).
//  k_mmd  : one wave per 64x64 pair-tile (upper triangle), fragments loaded
//           straight from L2 (G2 frag = contiguous 1KB block), HALF-K (128)
//           register-resident per step -> one vmcnt wait per half, 64-MFMA
//           burst under s_setprio. No LDS, no barriers in the hot path.
//           LAST block reduces the 256 slot accumulators and writes out.
//
// G2 layout: tile t (64 rows), frag(kc,fr) contiguous 1KB:
//   G2[t*16384 + (kc*4+fr)*512 + lane*8 + e]
//   row = t*64 + fr*16 + (lane&15); k = kc*32 + (lane>>4)*8 + e
// (A- and B-fragment layouts coincide for the Gram product.)
//
// ws doubles: d[0..255]=colsum, d[256]=neg_gamma2, d[257]=sqsum,
//             d[258..513]=slots; ints at byte 4112: tick_prep, tick_mmd;
//             float sq[8192] at 4608; bf16 G2[8192*256] at 40960.
#define WS_D_COLSUM 0
#define WS_D_NEGG   256
#define WS_D_SQSUM  257
#define WS_D_SLOT   258
#define WS_SLOTS    256
#define WS_TICK_OFF 4112
#define WS_SQ_OFF   4608
#define WS_G_OFF    40960

#define NROW 8192
#define HALF 4096
#define DIM  256
#define TT   64
#define NT   128                   // row-tiles
#define NPAIR (NT * (NT + 1) / 2)  // 8256
#define NBLK  (NPAIR / 4)          // 2064 blocks x 4 waves
#define TILE_US 16384              // ushorts per tile (32 KB)

typedef short  short8 __attribute__((ext_vector_type(8)));
typedef float  f32x4  __attribute__((ext_vector_type(4)));
typedef unsigned short us4 __attribute__((ext_vector_type(4)));

static __device__ __forceinline__ unsigned short f2bfbits(float f) {
    __hip_bfloat16 h = __float2bfloat16(f);   // RNE
    return *reinterpret_cast<unsigned short*>(&h);
}
static __device__ __forceinline__ float bfbits2f(unsigned short u) {
    return __uint_as_float(((unsigned int)u) << 16);
}

// ---------- kernel A: cvt->G2 + row-sq + colsum/sqsum + bandwidth ----------
// 256 blocks x 256 threads; block handles 32 rows; wave w rows r0+w+4i, i<8.
__global__ __launch_bounds__(256) void k_prep(const float* __restrict__ src,
                                              const float* __restrict__ tgt,
                                              unsigned short* __restrict__ G2,
                                              float* __restrict__ sq,
                                              double* __restrict__ wsd,
                                              int* __restrict__ tick) {
    __shared__ float cs_lds[4 * 256];
    __shared__ double sq_lds[4];
    __shared__ double red2[256];
    __shared__ int is_last;

    int t = threadIdx.x, wid = t >> 6, lane = t & 63;
    int r0 = blockIdx.x * 32;
    int c4 = lane * 4;
    // G2 lane-invariant part: kc=lane>>3, kl=(lane>>1)&3, e4=(lane&1)*4
    int lanepart = (lane >> 3) * 2048 + ((lane >> 1) & 3) * 128 + (lane & 1) * 4;

    float cs0 = 0.f, cs1 = 0.f, cs2 = 0.f, cs3 = 0.f;
    double wsq = 0.0;
    for (int i = 0; i < 8; ++i) {
        int row = r0 + wid + i * 4;
        const float* base = (row < HALF) ? (src + (size_t)row * DIM)
                                         : (tgt + (size_t)(row - HALF) * DIM);
        float4 v = *(const float4*)(base + c4);
        unsigned short u0 = f2bfbits(v.x), u1 = f2bfbits(v.y),
                       u2 = f2bfbits(v.z), u3 = f2bfbits(v.w);
        us4 uu = {u0, u1, u2, u3};
        size_t tb = (size_t)(row >> 6) * TILE_US + (((row >> 4) & 3) * 512) + ((row & 15) * 8);
        *(us4*)(G2 + tb + lanepart) = uu;
        float r0f = bfbits2f(u0), r1f = bfbits2f(u1),
              r2f = bfbits2f(u2), r3f = bfbits2f(u3);
        cs0 += r0f; cs1 += r1f; cs2 += r2f; cs3 += r3f;
        float s = r0f * r0f + r1f * r1f + r2f * r2f + r3f * r3f;
        #pragma unroll
        for (int off = 32; off; off >>= 1) s += __shfl_down(s, off);
        if (lane == 0) { sq[row] = s; wsq += (double)s; }
    }
    cs_lds[wid * 256 + c4 + 0] = cs0;
    cs_lds[wid * 256 + c4 + 1] = cs1;
    cs_lds[wid * 256 + c4 + 2] = cs2;
    cs_lds[wid * 256 + c4 + 3] = cs3;
    if (lane == 0) sq_lds[wid] = wsq;
    __syncthreads();
    double s = (double)cs_lds[t] + (double)cs_lds[256 + t] +
               (double)cs_lds[512 + t] + (double)cs_lds[768 + t];
    atomicAdd(&wsd[WS_D_COLSUM + t], s);
    if (t == 0)
        atomicAdd(&wsd[WS_D_SQSUM], sq_lds[0] + sq_lds[1] + sq_lds[2] + sq_lds[3]);

    // ---- last block computes bandwidth ----
    __threadfence();
    if (t == 0) is_last = (atomicAdd(tick, 1) == (int)gridDim.x - 1);
    __syncthreads();
    if (!is_last) return;
    double c = atomicAdd(&wsd[WS_D_COLSUM + t], 0.0);  // coherent read-back
    red2[t] = c * c;
    __syncthreads();
    for (int off = 128; off; off >>= 1) {
        if (t < off) red2[t] += red2[t + off];
        __syncthreads();
    }
    if (t == 0) {
        double S = atomicAdd(&wsd[WS_D_SQSUM], 0.0);
        const double N = (double)NROW;
        double sum_l2 = 2.0 * N * S - 2.0 * red2[0];
        double bw = sum_l2 / (N * N - N);
        bw = bw / 4.0;  // KERNEL_MUL ** (KERNEL_NUM//2) = 2^2
        wsd[WS_D_NEGG] = -1.4426950408889634 / (16.0 * bw);  // exp2 scaling
    }
}

// ---------- kernel D: one wave per 64x64 pair-tile, register-resident K ----
__global__ __launch_bounds__(256, 2) void k_mmd(const unsigned short* __restrict__ G2,
                                                const float* __restrict__ sq,
                                                const double* __restrict__ wsd,
                                                double* __restrict__ slots,
                                                float* __restrict__ out,
                                                int* __restrict__ tick) {
    __shared__ int is_last;
    __shared__ double fin[4];

    // XCD-chunked bijective swizzle (NBLK = 2064 = 8*258)
    int bid = blockIdx.x;
    int swz = (bid & 7) * (NBLK / 8) + (bid >> 3);

    int t = threadIdx.x, wid = t >> 6, lane = t & 63;
    int p = swz * 4 + wid;   // pair index 0..8255 (wave-uniform)

    // closed-form triangular decode: start(ti) = 128*ti - ti*(ti-1)/2
    int ti = (int)((257.0f - sqrtf(66049.0f - 8.0f * (float)p)) * 0.5f);
    ti = ti < 0 ? 0 : (ti > 127 ? 127 : ti);
    while (ti > 0 && p < 128 * ti - ((ti * (ti - 1)) >> 1)) --ti;
    while (p >= 128 * (ti + 1) - (((ti + 1) * ti) >> 1)) ++ti;
    int tj = ti + (p - (128 * ti - ((ti * (ti - 1)) >> 1)));

    const unsigned short* Ab = G2 + (size_t)ti * TILE_US;
    const unsigned short* Bb = G2 + (size_t)tj * TILE_US;
    int lo = lane * 8;

    const f32x4 zero4 = {0.f, 0.f, 0.f, 0.f};
    f32x4 acc[4][4];
    #pragma unroll
    for (int i = 0; i < 4; ++i)
        #pragma unroll
        for (int j = 0; j < 4; ++j) acc[i][j] = zero4;

    #pragma unroll
    for (int h = 0; h < 2; ++h) {
        short8 a[4][4], b[4][4];   // [kf][fr] — all compile-time indexed
        #pragma unroll
        for (int kf = 0; kf < 4; ++kf)
            #pragma unroll
            for (int fr = 0; fr < 4; ++fr) {
                int fo = (((h * 4 + kf) * 4 + fr) * 512) + lo;
                a[kf][fr] = *(const short8*)&Ab[fo];
                b[kf][fr] = *(const short8*)&Bb[fo];
            }
        __builtin_amdgcn_s_setprio(1);
        #pragma unroll
        for (int kf = 0; kf < 4; ++kf)
            #pragma unroll
            for (int i = 0; i < 4; ++i)
                #pragma unroll
                for (int j = 0; j < 4; ++j)
                    acc[i][j] = __builtin_amdgcn_mfma_f32_16x16x32_bf16(
                        a[kf][i], b[kf][j], acc[i][j], 0, 0, 0);
        __builtin_amdgcn_s_setprio(0);
    }

    // epilogue: x = l2*ng2 = min(sqa' + sqb' + acc*m2g, 0);  kernels = sum e^(2^i)
    // C/D layout (m89): col = lane&15, row = (lane>>4)*4 + reg
    int gi0 = ti * TT, gj0 = tj * TT;
    float ng2 = (float)wsd[WS_D_NEGG];       // negative
    float m2g = -2.0f * ng2;                 // positive
    int rl16 = lane & 15, rgrp = lane >> 4;

    float sqb4[4];
    #pragma unroll
    for (int j = 0; j < 4; ++j) sqb4[j] = sq[gj0 + j * 16 + rl16] * ng2;

    float tsum = 0.f;
    #pragma unroll
    for (int i = 0; i < 4; ++i) {
        float sqa4[4];
        #pragma unroll
        for (int rr = 0; rr < 4; ++rr)
            sqa4[rr] = sq[gi0 + i * 16 + rgrp * 4 + rr] * ng2;
        #pragma unroll
        for (int j = 0; j < 4; ++j) {
            #pragma unroll
            for (int rr = 0; rr < 4; ++rr) {
                float x = fminf(fmaf(acc[i][j][rr], m2g, sqa4[rr] + sqb4[j]), 0.f);
                float e   = exp2f(x);
                float e2  = e * e;
                float e4  = e2 * e2;
                float e8  = e4 * e4;
                float e16 = e8 * e8;
                tsum += (e + e2) + (e4 + e8) + e16;
            }
        }
    }

    float w = ((ti < NT / 2) == (tj < NT / 2)) ? 1.f : -1.f;
    if (ti != tj) w *= 2.f;   // off-diagonal tiles count twice (symmetry)
    double dsum = (double)tsum * (double)w;

    #pragma unroll
    for (int off = 32; off; off >>= 1) dsum += __shfl_down(dsum, off);
    if (lane == 0) atomicAdd(&slots[p & (WS_SLOTS - 1)], dsum);

    // ---- last block finalizes ----
    __syncthreads();
    __threadfence();
    if (t == 0) is_last = (atomicAdd(tick, 1) == (int)gridDim.x - 1);
    __syncthreads();
    if (!is_last) return;
    double v = atomicAdd(&slots[t], 0.0);  // coherent read-back
    #pragma unroll
    for (int off = 32; off; off >>= 1) v += __shfl_down(v, off);
    if (lane == 0) fin[wid] = v;
    __syncthreads();
    if (t == 0)
        out[0] = (float)((fin[0] + fin[1] + fin[2] + fin[3]) /
                         ((double)HALF * (double)HALF));
}

extern "C" void kernel_launch(void* const* d_in, const int* in_sizes, int n_in,
                              void* d_out, int out_size, void* d_ws, size_t ws_size,
                              hipStream_t stream) {
    const float* src = (const float*)d_in[0];
    const float* tgt = (const float*)d_in[1];
    float* out = (float*)d_out;

    double* wsd        = (double*)d_ws;
    int* ticks         = (int*)((char*)d_ws + WS_TICK_OFF);
    float* sq          = (float*)((char*)d_ws + WS_SQ_OFF);
    unsigned short* G2 = (unsigned short*)((char*)d_ws + WS_G_OFF);

    // zero colsum/negg/sqsum/slots/tickets every launch
    hipMemsetAsync(d_ws, 0, WS_SQ_OFF, stream);

    k_prep<<<NROW / 32, 256, 0, stream>>>(src, tgt, G2, sq, wsd, &ticks[0]);
    k_mmd<<<NBLK, 256, 0, stream>>>(G2, sq, wsd, &wsd[WS_D_SLOT], out, &ticks[1]);
}